// Round 5
// baseline (122.823 us; speedup 1.0000x reference)
//
#include <hip/hip_runtime.h>

// DifferentiableRankIntegration, B=1024, tau=0.1, K=60.
// sigma(a,b) = E_a/(E_a+E_b), E = exp2(clamp(s*log2(e)/tau, +-60)).
// Quad combining (exact): for 4 a-terms with elementary symmetric polys e1..e4
// of normalized E', and xs = x * rg (bucket scale):
//   sum_i E'_i/(E'_i+xs) = N(xs)/D(xs),
//   D = xs^4+e1 xs^3+e2 xs^2+e3 xs+e4,  N = e1 xs^3+2e2 xs^2+3e3 xs+4e4.
// -> 1 rcp per 4 ordered terms. Magnitude-bucketed compaction (ballot key =
// (cat-1)*4 + exponent-bucket) keeps every quad's E' in [2^-16,2^16] so all
// coefficients stay in fp32 range. xs clamped to [2^-30,2^30] (exact limits:
// N/D(0)=4-ish, N/D(inf)=0). v and l matrices ride the two lanes of packed
// f32 (v_pk_fma_f32). Dummy slots E'=0 are exact (factor (0+xs)).
//   AN[b](rank_pos sum) = S3+S2 ; AP[b](rank_neg sum) = S3+S1
// rank = (1+AN)*pf_b + (1+AP)*nf_b ; out = 61*(wv/(60+rk_v)+wl/(60+rk_l)).

typedef float f32x2 __attribute__((ext_vector_type(2)));

constexpr int B = 1024;
constexpr int NT = 256;
constexpr int NQMAX = 272;       // >= max total quads (<= (1024+36)/4 = 265)
constexpr int SLOTS = NQMAX * 4; // 1088
constexpr int DUMP = 1024;

// pool phase A: EcV[SLOTS] | EcL[SLOTS] | Cq[NQMAX*8] f32x2 | Rg[NQMAX] f32x2
// pool phase B (after main loop): A[4][1025] floats overlay
constexpr int POOL_BYTES = 2 * SLOTS * 4 + NQMAX * 8 * 8 + NQMAX * 8; // 28288

static __device__ __forceinline__ f32x2 vfma(f32x2 a, f32x2 b, f32x2 c) {
#if __has_builtin(__builtin_elementwise_fma)
    return __builtin_elementwise_fma(a, b, c);
#else
    f32x2 r; r.x = fmaf(a.x, b.x, c.x); r.y = fmaf(a.y, b.y, c.y); return r;
#endif
}
static __device__ __forceinline__ f32x2 vclamp(f32x2 x, float lo, float hi) {
    f32x2 r;
    r.x = fminf(fmaxf(x.x, lo), hi);   // -> v_med3_f32
    r.y = fminf(fmaxf(x.y, lo), hi);
    return r;
}

__global__ __launch_bounds__(NT, 2)
void rank_quad_kernel(const float* __restrict__ s_v,
                      const float* __restrict__ s_l,
                      const int* __restrict__ pos_m,
                      const int* __restrict__ neg_m,
                      const float* __restrict__ w_v,
                      const float* __restrict__ w_l,
                      float* __restrict__ out) {
    __shared__ __align__(16) char pool[POOL_BYTES];
    __shared__ unsigned short IdxV[SLOTS], IdxL[SLOTS];
    __shared__ int segCnt[2][12][16];   // [matrix][key][unit], unit = i*4+wave
    __shared__ int segP[2][12];         // padded seg lengths (mult of 4)

    float* EcV = (float*)pool;                 // raw E, compacted (v layout)
    float* EcL = EcV + SLOTS;                  // raw E, compacted (l layout)
    f32x2* Cq  = (f32x2*)(pool + 2 * SLOTS * 4);  // 8 coeffs per quad, (v,l)
    f32x2* Rg  = Cq + NQMAX * 8;               // per-quad scale, (v,l)

    const int r = blockIdx.x;
    const int tid = threadIdx.x;
    const int lane = tid & 63;
    const int wvid = tid >> 6;
    const float SCALE = 14.4269504088896340736f;  // log2(e)/tau

    for (int s = tid; s < SLOTS; s += NT) {
        EcV[s] = 0.f; EcL[s] = 0.f; IdxV[s] = DUMP; IdxL[s] = DUMP;
    }
    __syncthreads();

    // ---- Phase 1: read, categorize+bucket, ballot-count ----
    int cat[4]; int kv[4], kl[4], rkv[4], rkl[4]; float ev[4], el[4];
#pragma unroll
    for (int i = 0; i < 4; ++i) {
        const int c = tid + i * NT;
        float uv = fminf(fmaxf(s_v[r * B + c] * SCALE, -60.f), 60.f);
        float ul = fminf(fmaxf(s_l[r * B + c] * SCALE, -60.f), 60.f);
        ev[i] = exp2f(uv); el[i] = exp2f(ul);
        const int bv = min((int)((uv + 60.f) * (1.f / 30.f)), 3);
        const int bl = min((int)((ul + 60.f) * (1.f / 30.f)), 3);
        const int pf = pos_m[r * B + c] != 0;
        const int nf = neg_m[r * B + c] != 0;
        cat[i] = pf | (nf << 1);
        kv[i] = cat[i] ? (cat[i] - 1) * 4 + bv : -1;
        kl[i] = cat[i] ? (cat[i] - 1) * 4 + bl : -1;
        rkv[i] = 0; rkl[i] = 0;
#pragma unroll
        for (int k = 0; k < 12; ++k) {
            unsigned long long m = __ballot(kv[i] == k);
            if (kv[i] == k) rkv[i] = __popcll(m & ((1ull << lane) - 1ull));
            if (lane == 0) segCnt[0][k][i * 4 + wvid] = (int)__popcll(m);
            m = __ballot(kl[i] == k);
            if (kl[i] == k) rkl[i] = __popcll(m & ((1ull << lane) - 1ull));
            if (lane == 0) segCnt[1][k][i * 4 + wvid] = (int)__popcll(m);
        }
    }
    __syncthreads();

    // ---- Totals -> padded lengths (to LDS so runtime indexing stays in LDS) ----
    if (tid < 24) {
        const int mi = tid / 12, k = tid % 12;
        int t = 0;
#pragma unroll
        for (int u = 0; u < 16; ++u) t += segCnt[mi][k][u];
        segP[mi][k] = (t + 3) & ~3;
    }
    __syncthreads();

    // ---- Geometry (every thread, identical) ----
    int catpV[3], catpL[3];
#pragma unroll
    for (int c = 0; c < 3; ++c) {
        catpV[c] = segP[0][4*c] + segP[0][4*c+1] + segP[0][4*c+2] + segP[0][4*c+3];
        catpL[c] = segP[1][4*c] + segP[1][4*c+1] + segP[1][4*c+2] + segP[1][4*c+3];
    }
    const int Q0 = (catpV[0] > catpL[0] ? catpV[0] : catpL[0]) >> 2;
    const int Q1 = (catpV[1] > catpL[1] ? catpV[1] : catpL[1]) >> 2;
    const int Q2 = (catpV[2] > catpL[2] ? catpV[2] : catpL[2]) >> 2;
    const int qb1 = Q0, qb2 = Q0 + Q1, NQ = Q0 + Q1 + Q2;
    const int na64 = (4 * NQ + 63) & ~63;   // <= SLOTS

    // ---- Phase 2: deterministic placement (per matrix) ----
#pragma unroll
    for (int i = 0; i < 4; ++i) {
        if (cat[i]) {
            const int cm1 = cat[i] - 1;
            const int qbc = (cm1 == 0) ? 0 : (cm1 == 1) ? qb1 : qb2;
            const int unit = i * 4 + wvid;
            // v
            {
                const int k = kv[i];
                int base = 4 * qbc;
                for (int j = cm1 * 4; j < k; ++j) base += segP[0][j];
                int pre = 0;
                for (int u = 0; u < unit; ++u) pre += segCnt[0][k][u];
                const int slot = base + pre + rkv[i];
                EcV[slot] = ev[i]; IdxV[slot] = (unsigned short)(tid + i * NT);
            }
            // l
            {
                const int k = kl[i];
                int base = 4 * qbc;
                for (int j = cm1 * 4; j < k; ++j) base += segP[1][j];
                int pre = 0;
                for (int u = 0; u < unit; ++u) pre += segCnt[1][k][u];
                const int slot = base + pre + rkl[i];
                EcL[slot] = el[i]; IdxL[slot] = (unsigned short)(tid + i * NT);
            }
        }
    }
    __syncthreads();

    // ---- Phase 2.5: build per-quad coefficients (normalized by bucket scale) ----
    for (int q = tid; q < NQ; q += NT) {
        const int cm1 = (q >= qb1) + (q >= qb2);
        const int qbc = (cm1 == 0) ? 0 : (cm1 == 1) ? qb1 : qb2;
        const int sub = 4 * (q - qbc);
        const int kb = cm1 * 4;
        float cf[8][2]; float rg[2];
#pragma unroll
        for (int mi = 0; mi < 2; ++mi) {
            const int s1 = segP[mi][kb];
            const int s2 = s1 + segP[mi][kb + 1];
            const int s3 = s2 + segP[mi][kb + 2];
            const int bk = (sub >= s1) + (sub >= s2) + (sub >= s3);
            const float rgm = ldexpf(1.f, 45 - 30 * bk);
            const float* Ec = mi ? EcL : EcV;
            const float4 E4 = *(const float4*)&Ec[4 * q];
            const float e0 = E4.x * rgm, e1_ = E4.y * rgm;
            const float e2_ = E4.z * rgm, e3_ = E4.w * rgm;
            const float P1 = e0 * e1_, S1 = e0 + e1_;
            const float P2 = e2_ * e3_, S2 = e2_ + e3_;
            const float E1 = S1 + S2;
            const float E2 = fmaf(S1, S2, P1 + P2);
            const float E3 = fmaf(S1, P2, S2 * P1);
            const float E4c = P1 * P2;
            cf[0][mi] = E1;        cf[1][mi] = E2;
            cf[2][mi] = E3;        cf[3][mi] = E4c;
            cf[4][mi] = E1;        cf[5][mi] = 2.f * E2;
            cf[6][mi] = 3.f * E3;  cf[7][mi] = 4.f * E4c;
            rg[mi] = rgm;
        }
#pragma unroll
        for (int j = 0; j < 8; ++j) Cq[q * 8 + j] = (f32x2){cf[j][0], cf[j][1]};
        Rg[q] = (f32x2){rg[0], rg[1]};
    }
    __syncthreads();

    // ---- Main loop: 4 consecutive b-slots/thread, quads broadcast from LDS ----
    float a1v[4] = {0,0,0,0}, a2v[4] = {0,0,0,0}, a3v[4] = {0,0,0,0};
    float a1l[4] = {0,0,0,0}, a2l[4] = {0,0,0,0}, a3l[4] = {0,0,0,0};
    const int s0 = 4 * tid;

    if (s0 < na64) {
        const float4 xv4 = *(const float4*)&EcV[s0];
        const float4 xl4 = *(const float4*)&EcL[s0];
        f32x2 x2[4];
        x2[0] = (f32x2){xv4.x, xl4.x}; x2[1] = (f32x2){xv4.y, xl4.y};
        x2[2] = (f32x2){xv4.z, xl4.z}; x2[3] = (f32x2){xv4.w, xl4.w};

        auto run = [&](int q0, int qn, float* av, float* al) {
            for (int q = q0; q < qn; ++q) {
                const float4* row4 = (const float4*)(Cq + q * 8);
                const float4 A4 = row4[0], B4 = row4[1];
                const float4 C4 = row4[2], D4 = row4[3];
                const f32x2 c0 = {A4.x, A4.y}, c1 = {A4.z, A4.w};
                const f32x2 c2 = {B4.x, B4.y}, c3 = {B4.z, B4.w};
                const f32x2 c4 = {C4.x, C4.y}, c5 = {C4.z, C4.w};
                const f32x2 c6 = {D4.x, D4.y}, c7 = {D4.z, D4.w};
                const f32x2 rg = Rg[q];
#pragma unroll
                for (int i = 0; i < 4; ++i) {
                    f32x2 xs = x2[i] * rg;
                    xs = vclamp(xs, 0x1p-30f, 0x1p30f);
                    f32x2 t = xs + c0;
                    t = vfma(t, xs, c1);
                    t = vfma(t, xs, c2);
                    const f32x2 D = vfma(t, xs, c3);
                    f32x2 u = vfma(c4, xs, c5);
                    u = vfma(u, xs, c6);
                    const f32x2 N = vfma(u, xs, c7);
                    av[i] = fmaf(N.x, __builtin_amdgcn_rcpf(D.x), av[i]);
                    al[i] = fmaf(N.y, __builtin_amdgcn_rcpf(D.y), al[i]);
                }
            }
        };
        run(0,   qb1, a1v, a1l);   // cat1 segment-group -> AP side
        run(qb1, qb2, a2v, a2l);   // cat2 -> AN side
        run(qb2, NQ,  a3v, a3l);   // cat3 -> both
    }
    __syncthreads();   // all pool (Ec/Cq) reads done -> safe to overlay A

    // ---- Un-scatter ranks to original columns (A overlays the pool) ----
    float* A0 = (float*)pool;
    float* A1 = A0 + 1025;
    float* A2 = A1 + 1025;
    float* A3 = A2 + 1025;
#pragma unroll
    for (int i = 0; i < 4; ++i) {
        const int oiV = IdxV[s0 + i];
        const int oiL = IdxL[s0 + i];
        A0[oiV] = a3v[i] + a2v[i];   // ANv
        A1[oiV] = a3v[i] + a1v[i];   // APv
        A2[oiL] = a3l[i] + a2l[i];   // ANl
        A3[oiL] = a3l[i] + a1l[i];   // APl
    }
    __syncthreads();

    // ---- Coalesced epilogue ----
#pragma unroll
    for (int i = 0; i < 4; ++i) {
        const int c = tid + i * NT;
        const bool pf = (cat[i] & 1) != 0;
        const bool nf = (cat[i] & 2) != 0;
        const float rkv_ = (pf ? 1.f + A0[c] : 0.f) + (nf ? 1.f + A1[c] : 0.f);
        const float rkl_ = (pf ? 1.f + A2[c] : 0.f) + (nf ? 1.f + A3[c] : 0.f);
        out[r * B + c] = 61.f * (w_v[r * B + c] / (60.f + rkv_) +
                                 w_l[r * B + c] / (60.f + rkl_));
    }
}

extern "C" void kernel_launch(void* const* d_in, const int* in_sizes, int n_in,
                              void* d_out, int out_size, void* d_ws, size_t ws_size,
                              hipStream_t stream) {
    const float* s_v = (const float*)d_in[0];
    const float* s_l = (const float*)d_in[1];
    const int* pos_mask = (const int*)d_in[2];
    const int* neg_mask = (const int*)d_in[3];
    const float* w_v = (const float*)d_in[4];
    const float* w_l = (const float*)d_in[5];
    float* out = (float*)d_out;

    rank_quad_kernel<<<B, NT, 0, stream>>>(s_v, s_l, pos_mask, neg_mask,
                                           w_v, w_l, out);
}

// Round 6
// 113.219 us; speedup vs baseline: 1.0848x; 1.0848x over previous
//
#include <hip/hip_runtime.h>

// DifferentiableRankIntegration, B=1024, tau=0.1, K=60.
// sigma(a,b) = E_a/(E_a+E_b), E = exp2(clamp(s*log2(e)/tau, +-60)).
// Quad combining (exact): for 4 a-terms with elementary symmetric polys e1..e4
// of normalized E', and xs = x * rg (bucket scale):
//   sum_i E'_i/(E'_i+xs) = N(xs)/D(xs),
//   D = xs^4+e1 xs^3+e2 xs^2+e3 xs+e4,  N = e1 xs^3+2e2 xs^2+3e3 xs+4e4.
// Magnitude-bucketed compaction (key=(cat-1)*4+bucket, W=30) keeps E' in
// [2^-15,2^15]; xs clamped to [2^-30,2^30] (error <= 2^-15/term).
// R6: inline-asm v_pk_* (force packed f32, v&l in the two halves), and a
// per-cat run table so xs is computed once per (kv,kl)-run, not per quad.

typedef float f32x2 __attribute__((ext_vector_type(2)));

constexpr int B = 1024;
constexpr int NT = 256;
constexpr int NQMAX = 272;       // >= max total quads (<= (1024+36)/4 = 265)
constexpr int SLOTS = NQMAX * 4; // 1088
constexpr int DUMP = 1024;

// pool phase A: EcV[SLOTS] | EcL[SLOTS] | Cq[NQMAX*8] f32x2
// pool phase B (after main loop): A[4][1025] floats overlay
constexpr int POOL_BYTES = 2 * SLOTS * 4 + NQMAX * 8 * 8; // 26112

static __device__ __forceinline__ f32x2 pk_add(f32x2 a, f32x2 b) {
    f32x2 d;
    asm("v_pk_add_f32 %0, %1, %2" : "=v"(d) : "v"(a), "v"(b));
    return d;
}
static __device__ __forceinline__ f32x2 pk_mul(f32x2 a, f32x2 b) {
    f32x2 d;
    asm("v_pk_mul_f32 %0, %1, %2" : "=v"(d) : "v"(a), "v"(b));
    return d;
}
static __device__ __forceinline__ f32x2 pk_fma(f32x2 a, f32x2 b, f32x2 c) {
    f32x2 d;
    asm("v_pk_fma_f32 %0, %1, %2, %3" : "=v"(d) : "v"(a), "v"(b), "v"(c));
    return d;
}

__global__ __launch_bounds__(NT, 2)
void rank_quad_kernel(const float* __restrict__ s_v,
                      const float* __restrict__ s_l,
                      const int* __restrict__ pos_m,
                      const int* __restrict__ neg_m,
                      const float* __restrict__ w_v,
                      const float* __restrict__ w_l,
                      float* __restrict__ out) {
    __shared__ __align__(16) char pool[POOL_BYTES];
    __shared__ unsigned short IdxV[SLOTS], IdxL[SLOTS];
    __shared__ int segCnt[2][12][16];   // [matrix][key][unit], unit = i*4+wave
    __shared__ int segP[2][12];         // padded seg lengths (mult of 4)
    __shared__ int RunQ[3][9];          // run boundaries (quad idx) per cat
    __shared__ f32x2 RunRg[3][8];       // per-run (rg_v, rg_l)
    __shared__ int nRunsL[3];

    float* EcV = (float*)pool;                 // raw E, compacted (v layout)
    float* EcL = EcV + SLOTS;                  // raw E, compacted (l layout)
    f32x2* Cq  = (f32x2*)(pool + 2 * SLOTS * 4);  // 8 coeffs per quad, (v,l)

    const int r = blockIdx.x;
    const int tid = threadIdx.x;
    const int lane = tid & 63;
    const int wvid = tid >> 6;
    const float SCALE = 14.4269504088896340736f;  // log2(e)/tau

    for (int s = tid; s < SLOTS; s += NT) {
        EcV[s] = 0.f; EcL[s] = 0.f; IdxV[s] = DUMP; IdxL[s] = DUMP;
    }
    __syncthreads();

    // ---- Phase 1: read, categorize+bucket, ballot-count ----
    int cat[4]; int kv[4], kl[4], rkv[4], rkl[4]; float ev[4], el[4];
#pragma unroll
    for (int i = 0; i < 4; ++i) {
        const int c = tid + i * NT;
        float uv = fminf(fmaxf(s_v[r * B + c] * SCALE, -60.f), 60.f);
        float ul = fminf(fmaxf(s_l[r * B + c] * SCALE, -60.f), 60.f);
        ev[i] = exp2f(uv); el[i] = exp2f(ul);
        const int bv = min((int)((uv + 60.f) * (1.f / 30.f)), 3);
        const int bl = min((int)((ul + 60.f) * (1.f / 30.f)), 3);
        const int pf = pos_m[r * B + c] != 0;
        const int nf = neg_m[r * B + c] != 0;
        cat[i] = pf | (nf << 1);
        kv[i] = cat[i] ? (cat[i] - 1) * 4 + bv : -1;
        kl[i] = cat[i] ? (cat[i] - 1) * 4 + bl : -1;
        rkv[i] = 0; rkl[i] = 0;
#pragma unroll
        for (int k = 0; k < 12; ++k) {
            unsigned long long m = __ballot(kv[i] == k);
            if (kv[i] == k) rkv[i] = __popcll(m & ((1ull << lane) - 1ull));
            if (lane == 0) segCnt[0][k][i * 4 + wvid] = (int)__popcll(m);
            m = __ballot(kl[i] == k);
            if (kl[i] == k) rkl[i] = __popcll(m & ((1ull << lane) - 1ull));
            if (lane == 0) segCnt[1][k][i * 4 + wvid] = (int)__popcll(m);
        }
    }
    __syncthreads();

    // ---- Totals -> padded lengths ----
    if (tid < 24) {
        const int mi = tid / 12, k = tid % 12;
        int t = 0;
#pragma unroll
        for (int u = 0; u < 16; ++u) t += segCnt[mi][k][u];
        segP[mi][k] = (t + 3) & ~3;
    }
    __syncthreads();

    // ---- Geometry (every thread, identical) ----
    int catpV[3], catpL[3];
#pragma unroll
    for (int c = 0; c < 3; ++c) {
        catpV[c] = segP[0][4*c] + segP[0][4*c+1] + segP[0][4*c+2] + segP[0][4*c+3];
        catpL[c] = segP[1][4*c] + segP[1][4*c+1] + segP[1][4*c+2] + segP[1][4*c+3];
    }
    const int Q0 = (catpV[0] > catpL[0] ? catpV[0] : catpL[0]) >> 2;
    const int Q1 = (catpV[1] > catpL[1] ? catpV[1] : catpL[1]) >> 2;
    const int Q2 = (catpV[2] > catpL[2] ? catpV[2] : catpL[2]) >> 2;
    const int qb1 = Q0, qb2 = Q0 + Q1, NQ = Q0 + Q1 + Q2;
    const int na64 = (4 * NQ + 63) & ~63;   // <= SLOTS

    // ---- Phase 2: deterministic placement (per matrix) ----
#pragma unroll
    for (int i = 0; i < 4; ++i) {
        if (cat[i]) {
            const int cm1 = cat[i] - 1;
            const int qbc = (cm1 == 0) ? 0 : (cm1 == 1) ? qb1 : qb2;
            const int unit = i * 4 + wvid;
            {
                const int k = kv[i];
                int base = 4 * qbc;
                for (int j = cm1 * 4; j < k; ++j) base += segP[0][j];
                int pre = 0;
                for (int u = 0; u < unit; ++u) pre += segCnt[0][k][u];
                const int slot = base + pre + rkv[i];
                EcV[slot] = ev[i]; IdxV[slot] = (unsigned short)(tid + i * NT);
            }
            {
                const int k = kl[i];
                int base = 4 * qbc;
                for (int j = cm1 * 4; j < k; ++j) base += segP[1][j];
                int pre = 0;
                for (int u = 0; u < unit; ++u) pre += segCnt[1][k][u];
                const int slot = base + pre + rkl[i];
                EcL[slot] = el[i]; IdxL[slot] = (unsigned short)(tid + i * NT);
            }
        }
    }
    __syncthreads();

    // ---- Phase 2.5: per-quad coefficients (normalized by bucket scale) ----
    for (int q = tid; q < NQ; q += NT) {
        const int cm1 = (q >= qb1) + (q >= qb2);
        const int qbc = (cm1 == 0) ? 0 : (cm1 == 1) ? qb1 : qb2;
        const int sub = 4 * (q - qbc);
        const int kb = cm1 * 4;
        float cf[8][2];
#pragma unroll
        for (int mi = 0; mi < 2; ++mi) {
            const int s1 = segP[mi][kb];
            const int s2 = s1 + segP[mi][kb + 1];
            const int s3 = s2 + segP[mi][kb + 2];
            const int bk = (sub >= s1) + (sub >= s2) + (sub >= s3);
            const float rgm = ldexpf(1.f, 45 - 30 * bk);
            const float* Ec = mi ? EcL : EcV;
            const float4 E4 = *(const float4*)&Ec[4 * q];
            const float e0 = E4.x * rgm, e1_ = E4.y * rgm;
            const float e2_ = E4.z * rgm, e3_ = E4.w * rgm;
            const float P1 = e0 * e1_, S1 = e0 + e1_;
            const float P2 = e2_ * e3_, S2 = e2_ + e3_;
            const float E1 = S1 + S2;
            const float E2 = fmaf(S1, S2, P1 + P2);
            const float E3 = fmaf(S1, P2, S2 * P1);
            const float E4c = P1 * P2;
            cf[0][mi] = E1;        cf[1][mi] = E2;
            cf[2][mi] = E3;        cf[3][mi] = E4c;
            cf[4][mi] = E1;        cf[5][mi] = 2.f * E2;
            cf[6][mi] = 3.f * E3;  cf[7][mi] = 4.f * E4c;
        }
#pragma unroll
        for (int j = 0; j < 8; ++j) Cq[q * 8 + j] = (f32x2){cf[j][0], cf[j][1]};
    }

    // ---- Run tables: maximal q-ranges with constant (bucket_v, bucket_l) ----
    if (tid < 3) {
        const int cm1 = tid;
        const int qc0 = (cm1 == 0) ? 0 : (cm1 == 1) ? qb1 : qb2;
        const int qc1 = (cm1 == 0) ? qb1 : (cm1 == 1) ? qb2 : NQ;
        int qv[5], ql[5];
        qv[0] = qc0; ql[0] = qc0;
        int av_ = 0, al_ = 0;
        for (int k = 1; k <= 3; ++k) {
            av_ += segP[0][cm1 * 4 + k - 1] >> 2;
            al_ += segP[1][cm1 * 4 + k - 1] >> 2;
            qv[k] = min(qc0 + av_, qc1);
            ql[k] = min(qc0 + al_, qc1);
        }
        qv[4] = qc1; ql[4] = qc1;
        int ckv = 0, ckl = 0, q = qc0, nr = 0;
        while (q < qc1) {
            while (ckv < 3 && qv[ckv + 1] <= q) ++ckv;
            while (ckl < 3 && ql[ckl + 1] <= q) ++ckl;
            RunQ[cm1][nr] = q;
            RunRg[cm1][nr] = (f32x2){ldexpf(1.f, 45 - 30 * ckv),
                                     ldexpf(1.f, 45 - 30 * ckl)};
            int qn = qc1;
            if (ckv < 3 && qv[ckv + 1] > q) qn = min(qn, qv[ckv + 1]);
            if (ckl < 3 && ql[ckl + 1] > q) qn = min(qn, ql[ckl + 1]);
            q = qn; ++nr;
        }
        RunQ[cm1][nr] = qc1;
        nRunsL[cm1] = nr;
    }
    __syncthreads();

    // ---- Main loop: 4 consecutive b-slots/thread; per-run hoisted xs ----
    float a1v[4] = {0,0,0,0}, a2v[4] = {0,0,0,0}, a3v[4] = {0,0,0,0};
    float a1l[4] = {0,0,0,0}, a2l[4] = {0,0,0,0}, a3l[4] = {0,0,0,0};
    const int s0 = 4 * tid;

    if (s0 < na64) {
        const float4 xv4 = *(const float4*)&EcV[s0];
        const float4 xl4 = *(const float4*)&EcL[s0];
        f32x2 x2[4];
        x2[0] = (f32x2){xv4.x, xl4.x}; x2[1] = (f32x2){xv4.y, xl4.y};
        x2[2] = (f32x2){xv4.z, xl4.z}; x2[3] = (f32x2){xv4.w, xl4.w};

        auto runcat = [&](int cm1, float* av, float* al) {
            const int nr = nRunsL[cm1];
            for (int rix = 0; rix < nr; ++rix) {
                const int q0 = RunQ[cm1][rix];
                const int q1 = RunQ[cm1][rix + 1];
                const f32x2 rg = RunRg[cm1][rix];
                f32x2 xs[4];
#pragma unroll
                for (int i = 0; i < 4; ++i) {
                    f32x2 t = pk_mul(x2[i], rg);
                    t.x = fminf(fmaxf(t.x, 0x1p-30f), 0x1p30f);  // v_med3
                    t.y = fminf(fmaxf(t.y, 0x1p-30f), 0x1p30f);
                    xs[i] = t;
                }
                for (int q = q0; q < q1; ++q) {
                    const float4* row4 = (const float4*)(Cq + q * 8);
                    const float4 A4 = row4[0], B4 = row4[1];
                    const float4 C4 = row4[2], D4 = row4[3];
                    const f32x2 c0 = {A4.x, A4.y}, c1 = {A4.z, A4.w};
                    const f32x2 c2 = {B4.x, B4.y}, c3 = {B4.z, B4.w};
                    const f32x2 c4 = {C4.x, C4.y}, c5 = {C4.z, C4.w};
                    const f32x2 c6 = {D4.x, D4.y}, c7 = {D4.z, D4.w};
#pragma unroll
                    for (int i = 0; i < 4; ++i) {
                        f32x2 t = pk_add(xs[i], c0);
                        t = pk_fma(t, xs[i], c1);
                        t = pk_fma(t, xs[i], c2);
                        const f32x2 D = pk_fma(t, xs[i], c3);
                        f32x2 u = pk_fma(c4, xs[i], c5);
                        u = pk_fma(u, xs[i], c6);
                        const f32x2 N = pk_fma(u, xs[i], c7);
                        av[i] = fmaf(N.x, __builtin_amdgcn_rcpf(D.x), av[i]);
                        al[i] = fmaf(N.y, __builtin_amdgcn_rcpf(D.y), al[i]);
                    }
                }
            }
        };
        runcat(0, a1v, a1l);   // cat1 -> AP side
        runcat(1, a2v, a2l);   // cat2 -> AN side
        runcat(2, a3v, a3l);   // cat3 -> both
    }
    __syncthreads();   // all pool (Ec/Cq) reads done -> safe to overlay A

    // ---- Un-scatter ranks to original columns (A overlays the pool) ----
    float* A0 = (float*)pool;
    float* A1 = A0 + 1025;
    float* A2 = A1 + 1025;
    float* A3 = A2 + 1025;
#pragma unroll
    for (int i = 0; i < 4; ++i) {
        const int oiV = IdxV[s0 + i];
        const int oiL = IdxL[s0 + i];
        A0[oiV] = a3v[i] + a2v[i];   // ANv
        A1[oiV] = a3v[i] + a1v[i];   // APv
        A2[oiL] = a3l[i] + a2l[i];   // ANl
        A3[oiL] = a3l[i] + a1l[i];   // APl
    }
    __syncthreads();

    // ---- Coalesced epilogue ----
#pragma unroll
    for (int i = 0; i < 4; ++i) {
        const int c = tid + i * NT;
        const bool pf = (cat[i] & 1) != 0;
        const bool nf = (cat[i] & 2) != 0;
        const float rkv_ = (pf ? 1.f + A0[c] : 0.f) + (nf ? 1.f + A1[c] : 0.f);
        const float rkl_ = (pf ? 1.f + A2[c] : 0.f) + (nf ? 1.f + A3[c] : 0.f);
        out[r * B + c] = 61.f * (w_v[r * B + c] / (60.f + rkv_) +
                                 w_l[r * B + c] / (60.f + rkl_));
    }
}

extern "C" void kernel_launch(void* const* d_in, const int* in_sizes, int n_in,
                              void* d_out, int out_size, void* d_ws, size_t ws_size,
                              hipStream_t stream) {
    const float* s_v = (const float*)d_in[0];
    const float* s_l = (const float*)d_in[1];
    const int* pos_mask = (const int*)d_in[2];
    const int* neg_mask = (const int*)d_in[3];
    const float* w_v = (const float*)d_in[4];
    const float* w_l = (const float*)d_in[5];
    float* out = (float*)d_out;

    rank_quad_kernel<<<B, NT, 0, stream>>>(s_v, s_l, pos_mask, neg_mask,
                                           w_v, w_l, out);
}